// Round 27
// baseline (254.383 us; speedup 1.0000x reference)
//
#include <hip/hip_runtime.h>

// Problem constants
#define BDIM   16
#define PDIM   12
#define TDIM   4096
#define WINW   41
#define PADW   20
#define DDIM   492      // P*WIN
#define KCODES 1024

// MX-scaled fp8 MFMA (mfma_scale_f32_16x16x128_f8f6f4, scales=1.0) — R26
// verified (absmax 0, 59us). R26's limiter: 8192 ds_read_b128/CU = 41us of
// CU-level LDS throughput (70% utilized). R27: 32 rows/wave (2 A-slabs) at
// 512 threads -> each b128 read feeds 2 MFMAs -> 4096 reads/CU (20.5us LDS
// floor). Live ~100 <= the 128-VGPR pin of 512-thr blocks -> no spill at
// all (prologue peak ~80 also fits).
#define KCHUNK   4                   // K=128 chunks covering 512
#define TILE_BYTES (KCHUNK * 2 * 64 * 16)   // 8 KiB per 16-code tile

#define WAVES    8                   // 512-thread blocks
#define ROWS_WAVE 32                 // 2 slabs of 16 rows
#define BMROWS   (WAVES * ROWS_WAVE) // 256 rows per block
#define MROWS    (BDIM * TDIM)       // 65536
#define NBLK     (MROWS / BMROWS)    // 256 = 1 block/CU, single round
#define NQ       4                   // codebook quarters
#define QTILES   16                  // 16-code tiles per quarter
#define QBYTES   (QTILES * TILE_BYTES)   // 128 KiB

#define SCALE1   0x7F7F7F7F          // 4x e8m0(127) = 1.0 per 32-elem block

typedef __attribute__((ext_vector_type(4))) float f32x4;
typedef __attribute__((ext_vector_type(2))) long  long2v;
typedef __attribute__((ext_vector_type(4))) int   int4v;
typedef __attribute__((ext_vector_type(8))) int   int8v;

// two f32 pairs -> 4 e4m3 bytes (RNE, saturating) via v_cvt_pk_fp8_f32
__device__ __forceinline__ unsigned int pack4_fp8(float a, float b, float c, float d) {
    int v = 0;
    v = __builtin_amdgcn_cvt_pk_fp8_f32(a, b, v, false);  // bytes 0,1
    v = __builtin_amdgcn_cvt_pk_fp8_f32(c, d, v, true);   // bytes 2,3
    return (unsigned int)v;
}

__device__ __forceinline__ long pack8_fp8(const float* v) {
    unsigned int lo = pack4_fp8(v[0], v[1], v[2], v[3]);
    unsigned int hi = pack4_fp8(v[4], v[5], v[6], v[7]);
    return (long)(((unsigned long long)hi << 32) | lo);
}

// Pre-format codebook into fp8 B-fragments for mfma_scale_f32_16x16x128.
// Entry e = ((nt*KCHUNK + kc)*2 + half)*64 + lane holds 16 bytes:
//   B[k][n], n = nt*16 + (lane&15), k = kc*128 + (lane>>4)*32 + half*16 + jj
//   (jj = 0..15). Within a tile: offset = kc*2048 + half*1024 + lane*16 ->
//   both b128 reads per MFMA are 16B-stride (bank-conflict-free).
// IDENTICAL to R26 (verified absmax 0).
__global__ __launch_bounds__(256) void prep_bfrag_k(const float* __restrict__ cb,
                                                    long2v* __restrict__ bfrag) {
    int e    = blockIdx.x * 256 + threadIdx.x;   // 0..32767
    int lane = e & 63;
    int half = (e >> 6) & 1;
    int kc   = (e >> 7) & (KCHUNK - 1);
    int nt   = e >> 9;
    int n    = nt * 16 + (lane & 15);
    int k0   = kc * 128 + (lane >> 4) * 32 + half * 16;
    float v0[8], v1[8];
#pragma unroll
    for (int j = 0; j < 8; ++j) {
        int ka = k0 + j;
        int kb = k0 + 8 + j;
        v0[j] = (ka < DDIM) ? cb[n * DDIM + ka] : 0.f;
        v1[j] = (kb < DDIM) ? cb[n * DDIM + kb] : 0.f;
    }
    long2v out;
    out[0] = pack8_fp8(v0);
    out[1] = pack8_fp8(v1);
    bfrag[e] = out;
}

// Exact fp32 code norms.
__global__ __launch_bounds__(64) void prep_cnorm_k(const float* __restrict__ cb,
                                                   float* __restrict__ cnorm) {
    int n = blockIdx.x;
    int lane = threadIdx.x;
    float s = 0.f;
    for (int d = lane; d < DDIM; d += 64) { float c = cb[n * DDIM + d]; s += c * c; }
#pragma unroll
    for (int m = 1; m < 64; m <<= 1) s += __shfl_xor(s, m, 64);
    if (lane == 0) cnorm[n] = s;
}

// Exact sum of ||f||^2 over all rows via window multiplicity:
// mult(tt) = 41 - max(0,20-tt) - max(0,tt-4075).
__global__ __launch_bounds__(256) void xsq_k(const float* __restrict__ x,
                                             float* __restrict__ xsq_part) {
    float s = 0.f;
    for (int i = blockIdx.x * 256 + threadIdx.x; i < BDIM * PDIM * TDIM; i += 256 * 256) {
        int tt = i & (TDIM - 1);
        int mult = WINW - max(0, PADW - tt) - max(0, tt - (TDIM - 1 - PADW));
        float v = x[i];
        s += (float)mult * v * v;
    }
#pragma unroll
    for (int m = 1; m < 64; m <<= 1) s += __shfl_xor(s, m, 64);
    __shared__ float sm[4];
    if ((threadIdx.x & 63) == 0) sm[threadIdx.x >> 6] = s;
    __syncthreads();
    if (threadIdx.x == 0) xsq_part[blockIdx.x] = sm[0] + sm[1] + sm[2] + sm[3];
}

// Stage one 128 KiB quarter into LDS: 512 thr x 16 B = 8 KiB per round,
// 16 rounds -> 16 global_load_lds per thread.
__device__ __forceinline__ void stage_quarter(const unsigned char* __restrict__ gq,
                                              unsigned char* smem, int wave, int lane) {
#pragma unroll
    for (int i = 0; i < 16; ++i) {
        int off = i * 8192 + wave * 1024;
        __builtin_amdgcn_global_load_lds(
            (const __attribute__((address_space(1))) unsigned int*)(gq + off + lane * 16),
            (__attribute__((address_space(3))) unsigned int*)(smem + off),
            16, 0, 0);
    }
}

// windowed-x fetch: element d of row with time-index t
__device__ __forceinline__ float fetchx(const float* __restrict__ xb, int t, int d) {
    if (d >= DDIM) return 0.f;
    int p  = d / WINW;
    int w  = d - p * WINW;
    int tt = t + w - PADW;
    return (tt >= 0 && tt < TDIM) ? xb[p * TDIM + tt] : 0.f;
}

// Main sweep: 256 blocks (1/CU) x 8 waves x 32 rows (2 slabs of 16).
// Prologue: stage quarter 0 + sb table + 2-slab A-build + one sync. Then 4x
// { barrier-free sweep (16 tiles x 4 kc x {2 b128 reads, 2 MFMAs}); sync;
// restage; sync }. Each B read feeds BOTH slabs -> 4096 reads/CU.
__global__ __launch_bounds__(512)
void vq_main_k(const float* __restrict__ x,
               const unsigned char* __restrict__ bfrag,
               const float* __restrict__ cnorm,
               float* __restrict__ bpart) {
    __shared__ __align__(16) unsigned char smem[QBYTES];   // 128 KiB
    __shared__ float sb_lds[KCODES];                       // 4 KiB
    __shared__ float gsum[4 * WAVES];

    const int lane = threadIdx.x & 63;
    const int wave = threadIdx.x >> 6;
    const int col  = lane & 15;     // B/D column within 16-code tile
    const int hi   = lane >> 4;
    const int rowbase = blockIdx.x * BMROWS + wave * ROWS_WAVE;

    // Stage quarter 0; latency covered by sb-table + A-build below.
    stage_quarter(bfrag, smem, wave, lane);

    // Full bias table: sb_lds[n] = -0.5*||c_n||^2
    for (int i = threadIdx.x; i < KCODES; i += 512)
        sb_lds[i] = -0.5f * cnorm[i];

    // ---- fp8 A-build, 2 slabs: slab s row = rowbase + s*16 + col,
    //      k = kc*128 + hi*32 + 4m + b. sched_barrier per kc bounds peak. ----
    int8v afr0[KCHUNK], afr1[KCHUNK];
    {
        int row0 = rowbase + col;
        int t0 = row0 & (TDIM - 1);
        const float* xb0 = x + (size_t)(row0 >> 12) * (PDIM * TDIM);
        int row1 = rowbase + 16 + col;
        int t1 = row1 & (TDIM - 1);
        const float* xb1 = x + (size_t)(row1 >> 12) * (PDIM * TDIM);
#pragma unroll
        for (int kc = 0; kc < KCHUNK; ++kc) {
#pragma unroll
            for (int m = 0; m < 8; ++m) {
                int d = kc * 128 + hi * 32 + m * 4;
                afr0[kc][m] = (int)pack4_fp8(fetchx(xb0, t0, d + 0), fetchx(xb0, t0, d + 1),
                                             fetchx(xb0, t0, d + 2), fetchx(xb0, t0, d + 3));
            }
            __builtin_amdgcn_sched_barrier(0);
#pragma unroll
            for (int m = 0; m < 8; ++m) {
                int d = kc * 128 + hi * 32 + m * 4;
                afr1[kc][m] = (int)pack4_fp8(fetchx(xb1, t1, d + 0), fetchx(xb1, t1, d + 1),
                                             fetchx(xb1, t1, d + 2), fetchx(xb1, t1, d + 3));
            }
            __builtin_amdgcn_sched_barrier(0);
        }
    }

    float bs0[4], bs1[4];
#pragma unroll
    for (int r = 0; r < 4; ++r) { bs0[r] = -3.0e38f; bs1[r] = -3.0e38f; }

    // Entry drain: quarter 0 resident; sb_lds visible.
    __syncthreads();

    for (int q = 0; q < NQ; ++q) {
        // ---- Barrier-free sweep of the resident quarter ----
        for (int tl = 0; tl < QTILES; ++tl) {
            const unsigned char* tb = smem + tl * TILE_BYTES;
            f32x4 acc0 = {0.f, 0.f, 0.f, 0.f};
            f32x4 acc1 = {0.f, 0.f, 0.f, 0.f};
#pragma unroll
            for (int kc = 0; kc < KCHUNK; ++kc) {
                int4v blo = *(const int4v*)(tb + kc * 2048 + lane * 16);
                int4v bhi = *(const int4v*)(tb + kc * 2048 + 1024 + lane * 16);
                int8v b;
                b[0] = blo[0]; b[1] = blo[1]; b[2] = blo[2]; b[3] = blo[3];
                b[4] = bhi[0]; b[5] = bhi[1]; b[6] = bhi[2]; b[7] = bhi[3];
                acc0 = __builtin_amdgcn_mfma_scale_f32_16x16x128_f8f6f4(
                           afr0[kc], b, acc0, 0, 0, 0, SCALE1, 0, SCALE1);
                acc1 = __builtin_amdgcn_mfma_scale_f32_16x16x128_f8f6f4(
                           afr1[kc], b, acc1, 0, 0, 0, SCALE1, 0, SCALE1);
            }
            const float sb = sb_lds[q * (KCODES / NQ) + tl * 16 + col];
#pragma unroll
            for (int r = 0; r < 4; ++r) {        // D: col=lane&15, row=hi*4+r
                bs0[r] = fmaxf(bs0[r], acc0[r] + sb);
                bs1[r] = fmaxf(bs1[r], acc1[r] + sb);
            }
        }
        // ---- Restage next quarter (2 barriers per transition) ----
        if (q + 1 < NQ) {
            __syncthreads();   // all waves done reading smem
            stage_quarter(bfrag + (size_t)(q + 1) * QBYTES, smem, wave, lane);
            __syncthreads();   // drains vmcnt(0): next quarter resident
        }
    }

    // ---- Per-row max across the 16 col-lanes (masks<16 preserve hi) ----
#pragma unroll
    for (int m = 1; m < 16; m <<= 1)
#pragma unroll
        for (int r = 0; r < 4; ++r) {
            bs0[r] = fmaxf(bs0[r], __shfl_xor(bs0[r], m, 64));
            bs1[r] = fmaxf(bs1[r], __shfl_xor(bs1[r], m, 64));
        }

    // Lane col==0 of each 16-lane group owns rows {s*16 + hi*4 + r}.
    if (col == 0) {
        float s = 0.f;
#pragma unroll
        for (int r = 0; r < 4; ++r) s += bs0[r] + bs1[r];
        gsum[wave * 4 + hi] = s;
    }
    __syncthreads();
    if (threadIdx.x == 0) {
        float tot = 0.f;
#pragma unroll
        for (int i = 0; i < 4 * WAVES; ++i) tot += gsum[i];
        bpart[blockIdx.x] = tot;
    }
}

// loss = 0.25 * (Sxx - 2*sum_blocks bpart) / (65536*492)
__global__ __launch_bounds__(256) void finalize_k(const float* __restrict__ bpart,
                                                  const float* __restrict__ xsq_part,
                                                  float* __restrict__ out) {
    __shared__ double sm[256];
    int tid = threadIdx.x;
    sm[tid] = (double)bpart[tid];
    __syncthreads();
    for (int st = 128; st > 0; st >>= 1) {
        if (tid < st) sm[tid] += sm[tid + st];
        __syncthreads();
    }
    double S1 = sm[0];
    __syncthreads();
    sm[tid] = (double)xsq_part[tid];
    __syncthreads();
    for (int st = 128; st > 0; st >>= 1) {
        if (tid < st) sm[tid] += sm[tid + st];
        __syncthreads();
    }
    if (tid == 0)
        out[0] = (float)(0.25 * (sm[0] - 2.0 * S1) / ((double)MROWS * (double)DDIM));
}

extern "C" void kernel_launch(void* const* d_in, const int* in_sizes, int n_in,
                              void* d_out, int out_size, void* d_ws, size_t ws_size,
                              hipStream_t stream) {
    const float* x  = (const float*)d_in[0];   // (16,12,4096) f32
    const float* cb = (const float*)d_in[1];   // (1024,492) f32
    float* out = (float*)d_out;

    // workspace layout (~524 KiB)
    char* ws = (char*)d_ws;
    long2v* bfrag   = (long2v*)ws;                                  // 512 KiB
    float* cnorm    = (float*)(ws + (512u << 10));                  // 4 KiB
    float* xsq_part = (float*)(ws + (512u << 10) + 4096);           // 1 KiB
    float* bpart    = (float*)(ws + (512u << 10) + 8192);           // 1 KiB

    prep_bfrag_k<<<128, 256, 0, stream>>>(cb, bfrag);
    prep_cnorm_k<<<KCODES, 64, 0, stream>>>(cb, cnorm);
    xsq_k<<<256, 256, 0, stream>>>(x, xsq_part);
    vq_main_k<<<NBLK, 512, 0, stream>>>(x, (const unsigned char*)bfrag, cnorm, bpart);
    finalize_k<<<1, 256, 0, stream>>>(bpart, xsq_part, out);
}

// Round 28
// 61.013 us; speedup vs baseline: 4.1693x; 4.1693x over previous
//
#include <hip/hip_runtime.h>

// Problem constants
#define BDIM   16
#define PDIM   12
#define TDIM   4096
#define WINW   41
#define PADW   20
#define DDIM   492      // P*WIN
#define KCODES 1024

// MX-scaled fp8 MFMA (mfma_scale_f32_16x16x128_f8f6f4, scales=1.0) — R26
// verified (absmax 0, 59us steady / 61us graph). R26 accounting: LDS reads
// 8192 b128/CU = 41us (70% busy, binding); VALU 18us. R27 (2-slab B-reuse)
// spilled 757MB: the scale-MFMA's 8-reg tuple operands force aligned copies
// -> any 2-slab/2-chain variant exceeds the 512-thr 128-reg cap (R21/R27).
// R28 = R26 with the B tuple filled by direct ds_read_b128s into its halves
// (pointer-cast tuple writes) instead of 8 element movs per MFMA.
#define KCHUNK   4                   // K=128 chunks covering 512
#define TILE_BYTES (KCHUNK * 2 * 64 * 16)   // 8 KiB per 16-code tile

#define WAVES    16                  // 1024-thread blocks (4 waves/SIMD)
#define ROWS_WAVE 16
#define BMROWS   (WAVES * ROWS_WAVE) // 256 rows per block
#define MROWS    (BDIM * TDIM)       // 65536
#define NBLK     (MROWS / BMROWS)    // 256 = 1 block/CU, single round
#define NQ       4                   // codebook quarters
#define QTILES   16                  // 16-code tiles per quarter
#define QBYTES   (QTILES * TILE_BYTES)   // 128 KiB

#define SCALE1   0x7F7F7F7F          // 4x e8m0(127) = 1.0 per 32-elem block

typedef __attribute__((ext_vector_type(4))) float f32x4;
typedef __attribute__((ext_vector_type(2))) long  long2v;
typedef __attribute__((ext_vector_type(4))) int   int4v;
typedef __attribute__((ext_vector_type(8))) int   int8v;

// two f32 pairs -> 4 e4m3 bytes (RNE, saturating) via v_cvt_pk_fp8_f32
__device__ __forceinline__ unsigned int pack4_fp8(float a, float b, float c, float d) {
    int v = 0;
    v = __builtin_amdgcn_cvt_pk_fp8_f32(a, b, v, false);  // bytes 0,1
    v = __builtin_amdgcn_cvt_pk_fp8_f32(c, d, v, true);   // bytes 2,3
    return (unsigned int)v;
}

__device__ __forceinline__ long pack8_fp8(const float* v) {
    unsigned int lo = pack4_fp8(v[0], v[1], v[2], v[3]);
    unsigned int hi = pack4_fp8(v[4], v[5], v[6], v[7]);
    return (long)(((unsigned long long)hi << 32) | lo);
}

// Pre-format codebook into fp8 B-fragments for mfma_scale_f32_16x16x128.
// Entry e = ((nt*KCHUNK + kc)*2 + half)*64 + lane holds 16 bytes:
//   B[k][n], n = nt*16 + (lane&15), k = kc*128 + (lane>>4)*32 + half*16 + jj
//   (jj = 0..15). Within a tile: offset = kc*2048 + half*1024 + lane*16 ->
//   both b128 reads per MFMA are 16B-stride (bank-conflict-free).
// IDENTICAL to R26 (verified absmax 0).
__global__ __launch_bounds__(256) void prep_bfrag_k(const float* __restrict__ cb,
                                                    long2v* __restrict__ bfrag) {
    int e    = blockIdx.x * 256 + threadIdx.x;   // 0..32767
    int lane = e & 63;
    int half = (e >> 6) & 1;
    int kc   = (e >> 7) & (KCHUNK - 1);
    int nt   = e >> 9;
    int n    = nt * 16 + (lane & 15);
    int k0   = kc * 128 + (lane >> 4) * 32 + half * 16;
    float v0[8], v1[8];
#pragma unroll
    for (int j = 0; j < 8; ++j) {
        int ka = k0 + j;
        int kb = k0 + 8 + j;
        v0[j] = (ka < DDIM) ? cb[n * DDIM + ka] : 0.f;
        v1[j] = (kb < DDIM) ? cb[n * DDIM + kb] : 0.f;
    }
    long2v out;
    out[0] = pack8_fp8(v0);
    out[1] = pack8_fp8(v1);
    bfrag[e] = out;
}

// Exact fp32 code norms.
__global__ __launch_bounds__(64) void prep_cnorm_k(const float* __restrict__ cb,
                                                   float* __restrict__ cnorm) {
    int n = blockIdx.x;
    int lane = threadIdx.x;
    float s = 0.f;
    for (int d = lane; d < DDIM; d += 64) { float c = cb[n * DDIM + d]; s += c * c; }
#pragma unroll
    for (int m = 1; m < 64; m <<= 1) s += __shfl_xor(s, m, 64);
    if (lane == 0) cnorm[n] = s;
}

// Exact sum of ||f||^2 over all rows via window multiplicity:
// mult(tt) = 41 - max(0,20-tt) - max(0,tt-4075).
__global__ __launch_bounds__(256) void xsq_k(const float* __restrict__ x,
                                             float* __restrict__ xsq_part) {
    float s = 0.f;
    for (int i = blockIdx.x * 256 + threadIdx.x; i < BDIM * PDIM * TDIM; i += 256 * 256) {
        int tt = i & (TDIM - 1);
        int mult = WINW - max(0, PADW - tt) - max(0, tt - (TDIM - 1 - PADW));
        float v = x[i];
        s += (float)mult * v * v;
    }
#pragma unroll
    for (int m = 1; m < 64; m <<= 1) s += __shfl_xor(s, m, 64);
    __shared__ float sm[4];
    if ((threadIdx.x & 63) == 0) sm[threadIdx.x >> 6] = s;
    __syncthreads();
    if (threadIdx.x == 0) xsq_part[blockIdx.x] = sm[0] + sm[1] + sm[2] + sm[3];
}

// Stage one 128 KiB quarter into LDS: 1024 thr x 16 B = 16 KiB per round,
// 8 rounds -> 8 global_load_lds per thread.
__device__ __forceinline__ void stage_quarter(const unsigned char* __restrict__ gq,
                                              unsigned char* smem, int wave, int lane) {
#pragma unroll
    for (int i = 0; i < 8; ++i) {
        int off = i * 16384 + wave * 1024;
        __builtin_amdgcn_global_load_lds(
            (const __attribute__((address_space(1))) unsigned int*)(gq + off + lane * 16),
            (__attribute__((address_space(3))) unsigned int*)(smem + off),
            16, 0, 0);
    }
}

// windowed-x fetch: element d of row with time-index t
__device__ __forceinline__ float fetchx(const float* __restrict__ xb, int t, int d) {
    if (d >= DDIM) return 0.f;
    int p  = d / WINW;
    int w  = d - p * WINW;
    int tt = t + w - PADW;
    return (tt >= 0 && tt < TDIM) ? xb[p * TDIM + tt] : 0.f;
}

// Main sweep: 256 blocks (1/CU) x 16 waves x 16 rows, single round.
// Prologue: stage quarter 0 + sb table + A-build + one sync. Then 4x
// { barrier-free sweep (16 tiles x 4 MX-MFMAs x 8 b128 reads, zero sync
// inside); sync; restage; sync }. B tuple filled by direct tuple-half reads.
__global__ __launch_bounds__(1024)
void vq_main_k(const float* __restrict__ x,
               const unsigned char* __restrict__ bfrag,
               const float* __restrict__ cnorm,
               float* __restrict__ bpart) {
    __shared__ __align__(16) unsigned char smem[QBYTES];   // 128 KiB
    __shared__ float sb_lds[KCODES];                       // 4 KiB
    __shared__ float gsum[4 * WAVES];

    const int lane = threadIdx.x & 63;
    const int wave = threadIdx.x >> 6;
    const int col  = lane & 15;     // B/D column within 16-code tile
    const int hi   = lane >> 4;
    const int rowbase = blockIdx.x * BMROWS + wave * ROWS_WAVE;

    // Stage quarter 0; latency covered by sb-table + A-build below.
    stage_quarter(bfrag, smem, wave, lane);

    // Full bias table: sb_lds[n] = -0.5*||c_n||^2
    for (int i = threadIdx.x; i < KCODES; i += 1024)
        sb_lds[i] = -0.5f * cnorm[i];

    // ---- fp8 A-build: row = rowbase + col, k = kc*128 + hi*32 + 4m + b ----
    int8v afr[KCHUNK];
    {
        int row = rowbase + col;
        int t = row & (TDIM - 1);
        const float* xb = x + (size_t)(row >> 12) * (PDIM * TDIM);
#pragma unroll
        for (int kc = 0; kc < KCHUNK; ++kc) {
#pragma unroll
            for (int m = 0; m < 8; ++m) {
                int d = kc * 128 + hi * 32 + m * 4;
                float f0 = fetchx(xb, t, d + 0);
                float f1 = fetchx(xb, t, d + 1);
                float f2 = fetchx(xb, t, d + 2);
                float f3 = fetchx(xb, t, d + 3);
                afr[kc][m] = (int)pack4_fp8(f0, f1, f2, f3);
            }
            __builtin_amdgcn_sched_barrier(0);   // bound prologue pressure
        }
    }

    float bs[4];
#pragma unroll
    for (int r = 0; r < 4; ++r) bs[r] = -3.0e38f;

    // Entry drain: quarter 0 resident; sb_lds visible.
    __syncthreads();

    for (int q = 0; q < NQ; ++q) {
        // ---- Barrier-free sweep of the resident quarter ----
        for (int tl = 0; tl < QTILES; ++tl) {
            const unsigned char* tb = smem + tl * TILE_BYTES;
            f32x4 acc = {0.f, 0.f, 0.f, 0.f};
#pragma unroll
            for (int kc = 0; kc < KCHUNK; ++kc) {
                // Fill the operand tuple directly from LDS: two ds_read_b128
                // into b's halves (no element movs).
                int8v b;
                *(int4v*)&b         = *(const int4v*)(tb + kc * 2048 + lane * 16);
                *(((int4v*)&b) + 1) = *(const int4v*)(tb + kc * 2048 + 1024 + lane * 16);
                acc = __builtin_amdgcn_mfma_scale_f32_16x16x128_f8f6f4(
                          afr[kc], b, acc, 0, 0, 0, SCALE1, 0, SCALE1);
            }
            const float sb = sb_lds[q * (KCODES / NQ) + tl * 16 + col];
#pragma unroll
            for (int r = 0; r < 4; ++r)          // D: col=lane&15, row=hi*4+r
                bs[r] = fmaxf(bs[r], acc[r] + sb);
        }
        // ---- Restage next quarter (2 barriers per transition) ----
        if (q + 1 < NQ) {
            __syncthreads();   // all waves done reading smem
            stage_quarter(bfrag + (size_t)(q + 1) * QBYTES, smem, wave, lane);
            __syncthreads();   // drains vmcnt(0): next quarter resident
        }
    }

    // ---- Per-row max across the 16 col-lanes (masks<16 preserve hi) ----
#pragma unroll
    for (int m = 1; m < 16; m <<= 1)
#pragma unroll
        for (int r = 0; r < 4; ++r)
            bs[r] = fmaxf(bs[r], __shfl_xor(bs[r], m, 64));

    // Lane col==0 of each 16-lane group owns rows {hi*4 + r} of the slab.
    if (col == 0) {
        float s = 0.f;
#pragma unroll
        for (int r = 0; r < 4; ++r) s += bs[r];
        gsum[wave * 4 + hi] = s;
    }
    __syncthreads();
    if (threadIdx.x == 0) {
        float tot = 0.f;
#pragma unroll
        for (int i = 0; i < 4 * WAVES; ++i) tot += gsum[i];
        bpart[blockIdx.x] = tot;
    }
}

// loss = 0.25 * (Sxx - 2*sum_blocks bpart) / (65536*492)
__global__ __launch_bounds__(256) void finalize_k(const float* __restrict__ bpart,
                                                  const float* __restrict__ xsq_part,
                                                  float* __restrict__ out) {
    __shared__ double sm[256];
    int tid = threadIdx.x;
    sm[tid] = (double)bpart[tid];
    __syncthreads();
    for (int st = 128; st > 0; st >>= 1) {
        if (tid < st) sm[tid] += sm[tid + st];
        __syncthreads();
    }
    double S1 = sm[0];
    __syncthreads();
    sm[tid] = (double)xsq_part[tid];
    __syncthreads();
    for (int st = 128; st > 0; st >>= 1) {
        if (tid < st) sm[tid] += sm[tid + st];
        __syncthreads();
    }
    if (tid == 0)
        out[0] = (float)(0.25 * (sm[0] - 2.0 * S1) / ((double)MROWS * (double)DDIM));
}

extern "C" void kernel_launch(void* const* d_in, const int* in_sizes, int n_in,
                              void* d_out, int out_size, void* d_ws, size_t ws_size,
                              hipStream_t stream) {
    const float* x  = (const float*)d_in[0];   // (16,12,4096) f32
    const float* cb = (const float*)d_in[1];   // (1024,492) f32
    float* out = (float*)d_out;

    // workspace layout (~524 KiB)
    char* ws = (char*)d_ws;
    long2v* bfrag   = (long2v*)ws;                                  // 512 KiB
    float* cnorm    = (float*)(ws + (512u << 10));                  // 4 KiB
    float* xsq_part = (float*)(ws + (512u << 10) + 4096);           // 1 KiB
    float* bpart    = (float*)(ws + (512u << 10) + 8192);           // 1 KiB

    prep_bfrag_k<<<128, 256, 0, stream>>>(cb, bfrag);
    prep_cnorm_k<<<KCODES, 64, 0, stream>>>(cb, cnorm);
    xsq_k<<<256, 256, 0, stream>>>(x, xsq_part);
    vq_main_k<<<NBLK, 1024, 0, stream>>>(x, (const unsigned char*)bfrag, cnorm, bpart);
    finalize_k<<<1, 256, 0, stream>>>(bpart, xsq_part, out);
}